// Round 1
// baseline (1651.785 us; speedup 1.0000x reference)
//
#include <hip/hip_runtime.h>
#include <hip/hip_bf16.h>

// Problem constants (B=1)
#define T_SEQ   1024
#define C_MODEL 768
#define N_BR    12
#define DH      64
#define H_TOT   144          // N_BR * N_BR
#define NQ      9216         // C_MODEL * N_BR

// ---------------------------------------------------------------------------
// Generic fp32 GEMM: C[M,N] = alpha * (A[M,K] @ B[K,N]) + bias[N] (optional)
// 64x64 tile, BK=16, 256 threads, 4x4 micro-tile per thread.
// ---------------------------------------------------------------------------
__global__ __launch_bounds__(256)
void gemm_f32_kernel(const float* __restrict__ A, const float* __restrict__ B,
                     const float* __restrict__ bias, float* __restrict__ C,
                     int M, int N, int K, float alpha)
{
    __shared__ float As[16][65];   // transposed A tile: As[k][m], +1 pad
    __shared__ float Bs[16][65];   // Bs[k][n], +1 pad

    const int m0  = blockIdx.y * 64;
    const int n0  = blockIdx.x * 64;
    const int tid = threadIdx.x;
    const int ty  = tid >> 4;          // 0..15
    const int tx  = tid & 15;          // 0..15
    // loader mapping
    const int ar = tid >> 2;           // 0..63  (A tile row)
    const int ak = (tid & 3) << 2;     // 0,4,8,12 (A tile k offset)
    const int br = tid >> 4;           // 0..15  (B tile row)
    const int bc = (tid & 15) << 2;    // 0..60  (B tile col offset)

    float acc[4][4] = {};

    for (int k0 = 0; k0 < K; k0 += 16) {
        float4 av = *reinterpret_cast<const float4*>(&A[(size_t)(m0 + ar) * K + k0 + ak]);
        float4 bv = *reinterpret_cast<const float4*>(&B[(size_t)(k0 + br) * N + n0 + bc]);
        As[ak + 0][ar] = av.x; As[ak + 1][ar] = av.y;
        As[ak + 2][ar] = av.z; As[ak + 3][ar] = av.w;
        Bs[br][bc + 0] = bv.x; Bs[br][bc + 1] = bv.y;
        Bs[br][bc + 2] = bv.z; Bs[br][bc + 3] = bv.w;
        __syncthreads();
        #pragma unroll
        for (int k = 0; k < 16; ++k) {
            float a[4], b[4];
            #pragma unroll
            for (int i = 0; i < 4; ++i) a[i] = As[k][4 * ty + i];
            #pragma unroll
            for (int j = 0; j < 4; ++j) b[j] = Bs[k][4 * tx + j];
            #pragma unroll
            for (int i = 0; i < 4; ++i)
                #pragma unroll
                for (int j = 0; j < 4; ++j)
                    acc[i][j] = fmaf(a[i], b[j], acc[i][j]);
        }
        __syncthreads();
    }

    #pragma unroll
    for (int i = 0; i < 4; ++i) {
        const int row = m0 + 4 * ty + i;
        #pragma unroll
        for (int j = 0; j < 4; ++j) {
            const int col = n0 + 4 * tx + j;
            float v = alpha * acc[i][j];
            if (bias) v += bias[col];
            C[(size_t)row * N + col] = v;
        }
    }
}

// ---------------------------------------------------------------------------
// Fused wedge (x @ M[h], M[h] = I + (A - A^T) + diag(id_bias[h])) + RoPE.
// grid = (H_TOT, T/64), block = 256.
// outMode 0: Y[t*NQ + h*64 + c]  (in-place on Q buffer)
// outMode 1: Y[(h*T + t)*64 + c] (head-major K2)
// ---------------------------------------------------------------------------
__global__ __launch_bounds__(256)
void wedge_rope_kernel(const float* __restrict__ X, float* __restrict__ Y,
                       const float* __restrict__ Amat, const float* __restrict__ id_bias,
                       int inStride, int inHeadMod, int outMode)
{
    const int h   = blockIdx.x;
    const int t0  = blockIdx.y * 64;
    const int tid = threadIdx.x;

    __shared__ float Ms[64][65];   // M[d][e]
    __shared__ float Xs[64][65];   // input tile (t_local, d)

    // build M[h]
    for (int idx = tid; idx < 4096; idx += 256) {
        const int d = idx >> 6, e = idx & 63;
        float v = Amat[d * 64 + e] - Amat[e * 64 + d];
        if (d == e) v += 1.0f + id_bias[h * 64 + d];
        Ms[d][e] = v;
    }
    // load input tile
    const int cbase = (h % inHeadMod) * 64;
    for (int idx = tid; idx < 1024; idx += 256) {
        const int r  = idx >> 4;
        const int dq = (idx & 15) << 2;
        float4 v = *reinterpret_cast<const float4*>(&X[(size_t)(t0 + r) * inStride + cbase + dq]);
        Xs[r][dq + 0] = v.x; Xs[r][dq + 1] = v.y;
        Xs[r][dq + 2] = v.z; Xs[r][dq + 3] = v.w;
    }
    __syncthreads();

    const int r = tid >> 2;   // row 0..63
    const int q = tid & 3;    // channel quarter

    float y[16];
    #pragma unroll
    for (int ee = 0; ee < 16; ++ee) {
        const int e = q * 16 + ee;
        float accv = 0.f;
        #pragma unroll 8
        for (int d = 0; d < 64; ++d)
            accv = fmaf(Xs[r][d], Ms[d][e], accv);
        y[ee] = accv;
    }

    // RoPE: this thread owns channels [16q,16q+16) = 8 complete (2i,2i+1) pairs
    const int t = t0 + r;
    const float log1e4_inv32 = logf(10000.f) * (1.0f / 32.0f);
    #pragma unroll
    for (int p = 0; p < 8; ++p) {
        const int i = q * 8 + p;           // 0..31
        const float inv_freq = expf(-(float)i * log1e4_inv32);
        const float fr = (float)t * inv_freq;
        const float cs = cosf(fr);
        const float sn = sinf(fr);
        const float x1 = y[2 * p];
        const float x2 = y[2 * p + 1];
        const float o1 = x1 * cs - x2 * sn;   // channel i
        const float o2 = x1 * sn + x2 * cs;   // channel 32+i
        if (outMode == 0) {
            Y[(size_t)t * NQ + h * 64 + i]      = o1;
            Y[(size_t)t * NQ + h * 64 + 32 + i] = o2;
        } else {
            Y[((size_t)h * T_SEQ + t) * 64 + i]      = o1;
            Y[((size_t)h * T_SEQ + t) * 64 + 32 + i] = o2;
        }
    }
}

// ---------------------------------------------------------------------------
// mean over branches of WO_b -> mbias[768]
// ---------------------------------------------------------------------------
__global__ void mean_bias_kernel(const float* __restrict__ WO_b, float* __restrict__ mb)
{
    const int d = blockIdx.x * 256 + threadIdx.x;
    if (d < C_MODEL) {
        float s = 0.f;
        #pragma unroll
        for (int n = 0; n < N_BR; ++n) s += WO_b[n * C_MODEL + d];
        mb[d] = s * (1.0f / 12.0f);
    }
}

// ---------------------------------------------------------------------------
// Flash attention with sink, fp32. grid = (H_TOT, T/64), block = 256.
// Q is read from QC (layout (t, h*64+d)) and ctx is written IN-PLACE to the
// same region (same block owns both, staged through LDS first).
// K2: (144, 1024, 64). Vb: (1024, 768) -> head s = h%12 columns.
// ---------------------------------------------------------------------------
__global__ __launch_bounds__(256)
void attn_kernel(float* QC,                         // Q in / ctx out (aliased)
                 const float* __restrict__ K2,
                 const float* __restrict__ Vb,
                 const float* __restrict__ sink,
                 const float* __restrict__ v_nulls)
{
    const int h   = blockIdx.x;     // 0..143
    const int qt  = blockIdx.y;     // 0..15
    const int s   = h % N_BR;
    const int tid = threadIdx.x;
    const int ty  = tid >> 4;       // 0..15 -> rows 4ty..4ty+3
    const int tx  = tid & 15;       // 0..15 -> cols 4tx..4tx+3

    __shared__ float Qs[64][65];
    __shared__ float KPs[64][65];   // K tile, reused as P after S-compute
    __shared__ float Vs[64][64];

    // stage Q tile
    for (int idx = tid; idx < 1024; idx += 256) {
        const int r  = idx >> 4;
        const int dq = (idx & 15) << 2;
        float4 v = *reinterpret_cast<const float4*>(&QC[(size_t)(qt * 64 + r) * NQ + h * 64 + dq]);
        Qs[r][dq + 0] = v.x; Qs[r][dq + 1] = v.y;
        Qs[r][dq + 2] = v.z; Qs[r][dq + 3] = v.w;
    }

    float acc[4][4] = {};
    float m_i[4], l_i[4];
    #pragma unroll
    for (int i = 0; i < 4; ++i) { m_i[i] = -__builtin_inff(); l_i[i] = 0.f; }

    __syncthreads();

    for (int kt = 0; kt <= qt; ++kt) {
        // stage K and V tiles
        for (int idx = tid; idx < 1024; idx += 256) {
            const int r  = idx >> 4;
            const int dq = (idx & 15) << 2;
            float4 kv = *reinterpret_cast<const float4*>(&K2[((size_t)h * T_SEQ + kt * 64 + r) * 64 + dq]);
            KPs[r][dq + 0] = kv.x; KPs[r][dq + 1] = kv.y;
            KPs[r][dq + 2] = kv.z; KPs[r][dq + 3] = kv.w;
            float4 vv = *reinterpret_cast<const float4*>(&Vb[(size_t)(kt * 64 + r) * C_MODEL + s * 64 + dq]);
            Vs[r][dq + 0] = vv.x; Vs[r][dq + 1] = vv.y;
            Vs[r][dq + 2] = vv.z; Vs[r][dq + 3] = vv.w;
        }
        __syncthreads();

        // S = (Q @ K^T) * scale
        float sv[4][4] = {};
        for (int d = 0; d < 64; ++d) {
            float qv[4], kv[4];
            #pragma unroll
            for (int i = 0; i < 4; ++i) qv[i] = Qs[4 * ty + i][d];
            #pragma unroll
            for (int j = 0; j < 4; ++j) kv[j] = KPs[4 * tx + j][d];
            #pragma unroll
            for (int i = 0; i < 4; ++i)
                #pragma unroll
                for (int j = 0; j < 4; ++j)
                    sv[i][j] = fmaf(qv[i], kv[j], sv[i][j]);
        }
        #pragma unroll
        for (int i = 0; i < 4; ++i)
            #pragma unroll
            for (int j = 0; j < 4; ++j) {
                sv[i][j] *= 0.125f;
                if (kt == qt && (4 * tx + j) > (4 * ty + i)) sv[i][j] = -__builtin_inff();
            }

        // online softmax row stats (rows owned by the 16 lanes sharing ty)
        float scl[4];
        #pragma unroll
        for (int i = 0; i < 4; ++i) {
            float rm = fmaxf(fmaxf(sv[i][0], sv[i][1]), fmaxf(sv[i][2], sv[i][3]));
            #pragma unroll
            for (int w = 8; w >= 1; w >>= 1) rm = fmaxf(rm, __shfl_xor(rm, w));
            const float mn = fmaxf(m_i[i], rm);
            float rsum = 0.f;
            #pragma unroll
            for (int j = 0; j < 4; ++j) {
                sv[i][j] = __expf(sv[i][j] - mn);   // exp(-inf)=0 for masked
                rsum += sv[i][j];
            }
            #pragma unroll
            for (int w = 8; w >= 1; w >>= 1) rsum += __shfl_xor(rsum, w);
            scl[i] = __expf(m_i[i] - mn);           // 0 on first tile
            l_i[i] = l_i[i] * scl[i] + rsum;
            m_i[i] = mn;
        }

        __syncthreads();   // all K reads done -> safe to overwrite KPs with P

        #pragma unroll
        for (int i = 0; i < 4; ++i)
            #pragma unroll
            for (int j = 0; j < 4; ++j)
                KPs[4 * ty + i][4 * tx + j] = sv[i][j];
        #pragma unroll
        for (int i = 0; i < 4; ++i)
            #pragma unroll
            for (int d = 0; d < 4; ++d)
                acc[i][d] *= scl[i];

        __syncthreads();   // P visible

        // acc += P @ V
        for (int j = 0; j < 64; ++j) {
            float pv[4], vv[4];
            #pragma unroll
            for (int i = 0; i < 4; ++i) pv[i] = KPs[4 * ty + i][j];
            #pragma unroll
            for (int d = 0; d < 4; ++d) vv[d] = Vs[j][4 * tx + d];
            #pragma unroll
            for (int i = 0; i < 4; ++i)
                #pragma unroll
                for (int d = 0; d < 4; ++d)
                    acc[i][d] = fmaf(pv[i], vv[d], acc[i][d]);
        }
        __syncthreads();   // PV reads done before next tile load
    }

    // sink finalization + normalize + write ctx (in-place over Q region)
    const float snk = sink[h];
    #pragma unroll
    for (int i = 0; i < 4; ++i) {
        const float mt = fmaxf(m_i[i], snk);
        const float em = __expf(m_i[i] - mt);
        const float es = __expf(snk - mt);
        const float li = l_i[i] * em + es;
        const float oscale = em / li;
        const float psink  = es / li;
        const int trow = qt * 64 + 4 * ty + i;
        #pragma unroll
        for (int d = 0; d < 4; ++d) {
            const int col = 4 * tx + d;
            const float outv = acc[i][d] * oscale + psink * v_nulls[h * 64 + col];
            QC[(size_t)trow * NQ + h * 64 + col] = outv;
        }
    }
}

// ---------------------------------------------------------------------------
// launcher
// ---------------------------------------------------------------------------
extern "C" void kernel_launch(void* const* d_in, const int* in_sizes, int n_in,
                              void* d_out, int out_size, void* d_ws, size_t ws_size,
                              hipStream_t stream)
{
    (void)in_sizes; (void)n_in; (void)out_size; (void)ws_size;

    const float* x       = (const float*)d_in[0];
    const float* WV_w    = (const float*)d_in[1];
    const float* WV_b    = (const float*)d_in[2];
    const float* WK_w    = (const float*)d_in[3];
    const float* WK_b    = (const float*)d_in[4];
    const float* WQ_w    = (const float*)d_in[5];
    const float* Amat    = (const float*)d_in[6];
    const float* id_bias = (const float*)d_in[7];
    const float* sink    = (const float*)d_in[8];
    const float* v_nulls = (const float*)d_in[9];
    const float* WO_w    = (const float*)d_in[10];
    const float* WO_b    = (const float*)d_in[11];
    float* out = (float*)d_out;

    float* ws    = (float*)d_ws;
    float* qbuf  = ws;                                  // T * NQ          (Q -> ctx, in-place)
    float* k2    = qbuf  + (size_t)T_SEQ * NQ;          // H_TOT * T * 64
    float* kbase = k2    + (size_t)H_TOT * T_SEQ * DH;  // T * C
    float* vbase = kbase + (size_t)T_SEQ * C_MODEL;     // T * C
    float* mbias = vbase + (size_t)T_SEQ * C_MODEL;     // C

    const dim3 blk(256);

    // input projections
    gemm_f32_kernel<<<dim3(NQ / 64, T_SEQ / 64), blk, 0, stream>>>(
        x, WQ_w, nullptr, qbuf, T_SEQ, NQ, C_MODEL, 1.0f);
    gemm_f32_kernel<<<dim3(C_MODEL / 64, T_SEQ / 64), blk, 0, stream>>>(
        x, WK_w, WK_b, kbase, T_SEQ, C_MODEL, C_MODEL, 1.0f);
    gemm_f32_kernel<<<dim3(C_MODEL / 64, T_SEQ / 64), blk, 0, stream>>>(
        x, WV_w, WV_b, vbase, T_SEQ, C_MODEL, C_MODEL, 1.0f);

    // wedge + rope (Q in-place; K expanded to 144 heads, head-major)
    wedge_rope_kernel<<<dim3(H_TOT, T_SEQ / 64), blk, 0, stream>>>(
        qbuf, qbuf, Amat, id_bias, NQ, H_TOT, 0);
    wedge_rope_kernel<<<dim3(H_TOT, T_SEQ / 64), blk, 0, stream>>>(
        kbase, k2, Amat, id_bias, C_MODEL, N_BR, 1);

    // mean output bias
    mean_bias_kernel<<<dim3(3), blk, 0, stream>>>(WO_b, mbias);

    // attention with sink (ctx written in-place over Q)
    attn_kernel<<<dim3(H_TOT, T_SEQ / 64), blk, 0, stream>>>(
        qbuf, k2, vbase, sink, v_nulls);

    // out = (1/12) * ctx @ WO_flat + mean(WO_b)
    gemm_f32_kernel<<<dim3(C_MODEL / 64, T_SEQ / 64), blk, 0, stream>>>(
        qbuf, WO_w, mbias, out, T_SEQ, C_MODEL, NQ, 1.0f / 12.0f);
}

// Round 2
// 849.782 us; speedup vs baseline: 1.9438x; 1.9438x over previous
//
#include <hip/hip_runtime.h>
#include <hip/hip_bf16.h>

// Problem constants (B=1)
#define T_SEQ   1024
#define C_MODEL 768
#define N_BR    12
#define DH      64
#define H_TOT   144          // N_BR * N_BR
#define NQ      9216         // C_MODEL * N_BR

typedef __bf16 bf16x8 __attribute__((ext_vector_type(8)));
typedef float  f32x4  __attribute__((ext_vector_type(4)));
typedef unsigned short u16;

// ---------------------------------------------------------------------------
// helpers
// ---------------------------------------------------------------------------
__device__ __forceinline__ void gload16(void* lds, const void* g)
{
    __builtin_amdgcn_global_load_lds(
        (const __attribute__((address_space(1))) void*)g,
        (__attribute__((address_space(3))) void*)lds, 16, 0, 0);
}

__device__ __forceinline__ void split1(float x, u16& h, u16& l)
{
    __bf16 bh = (__bf16)x;
    __bf16 bl = (__bf16)(x - (float)bh);
    h = __builtin_bit_cast(u16, bh);
    l = __builtin_bit_cast(u16, bl);
}

// ---------------------------------------------------------------------------
// elementwise fp32 -> (hi, lo) bf16 split, same layout. n % 1024 == 0.
// ---------------------------------------------------------------------------
__global__ __launch_bounds__(256)
void split_kernel(const float* __restrict__ in, u16* __restrict__ hi,
                  u16* __restrict__ lo, int n)
{
    const int i = (blockIdx.x * 256 + threadIdx.x) * 4;
    if (i >= n) return;
    float4 v = *reinterpret_cast<const float4*>(&in[i]);
    u16 h0,h1,h2,h3,l0,l1,l2,l3;
    split1(v.x,h0,l0); split1(v.y,h1,l1); split1(v.z,h2,l2); split1(v.w,h3,l3);
    hi[i+0]=h0; hi[i+1]=h1; hi[i+2]=h2; hi[i+3]=h3;
    lo[i+0]=l0; lo[i+1]=l1; lo[i+2]=l2; lo[i+3]=l3;
}

// ---------------------------------------------------------------------------
// transpose + split: W[K][N] fp32 -> Wt_hi/lo[N][K] bf16. K,N % 32 == 0.
// grid = (N/32, K/32), block = 256.
// ---------------------------------------------------------------------------
__global__ __launch_bounds__(256)
void split_t_kernel(const float* __restrict__ W, u16* __restrict__ hi,
                    u16* __restrict__ lo, int K, int N)
{
    __shared__ float t[32][33];
    const int n0 = blockIdx.x * 32;
    const int k0 = blockIdx.y * 32;
    const int tx = threadIdx.x & 31;
    const int ty = threadIdx.x >> 5;      // 0..7
    #pragma unroll
    for (int r = 0; r < 4; ++r)
        t[ty + r * 8][tx] = W[(size_t)(k0 + ty + r * 8) * N + n0 + tx];
    __syncthreads();
    #pragma unroll
    for (int r = 0; r < 4; ++r) {
        const float v = t[tx][ty + r * 8];
        u16 h, l;
        split1(v, h, l);
        const size_t o = (size_t)(n0 + ty + r * 8) * K + k0 + tx;
        hi[o] = h; lo[o] = l;
    }
}

// ---------------------------------------------------------------------------
// Split-bf16 MFMA GEMM (NT): Cp[z] = Ah@Bh^T + Ah@Bl^T + Al@Bh^T over k-chunk z.
// A: [M][K] bf16 (hi/lo), B: [N][K] bf16 (hi/lo, transposed), Cp: [Z][M][N] f32 raw.
// 128x128 tile, BK=32, 256 threads (4 waves, 2x2), m97 structure.
// ---------------------------------------------------------------------------
#define BM 128
#define BN 128
#define BK 32

__global__ __launch_bounds__(256)
void gemm_split_kernel(const u16* __restrict__ Ah, const u16* __restrict__ Al,
                       const u16* __restrict__ Bh, const u16* __restrict__ Bl,
                       float* __restrict__ Cp, int M, int N, int K)
{
    __shared__ u16 sAh[BM * BK], sAl[BM * BK], sBh[BN * BK], sBl[BN * BK];

    const int tid  = threadIdx.x;
    const int lane = tid & 63;
    const int wid  = tid >> 6;
    const int m0   = blockIdx.y * BM;
    const int n0   = blockIdx.x * BN;
    const int kc   = K / gridDim.z;
    const int kbeg = blockIdx.z * kc;
    const int kend = kbeg + kc;

    const int wm = (wid >> 1) * 64;
    const int wn = (wid & 1) * 64;

    f32x4 acc[4][4];
    #pragma unroll
    for (int i = 0; i < 4; ++i)
        #pragma unroll
        for (int j = 0; j < 4; ++j)
            #pragma unroll
            for (int r = 0; r < 4; ++r) acc[i][j][r] = 0.f;

    // staging map: 16B unit u = (0..511): row = u>>2, k-chunk = u&3
    const int r0 = tid >> 2;       // 0..63
    const int c0 = tid & 3;        // 0..3 -> k offset c0*8

    const int rA = wm + (lane & 15);
    const int rB = wn + (lane & 15);
    const int co = (lane >> 4) * 8;      // k offset within tile

    for (int k0 = kbeg; k0 < kend; k0 += BK) {
        gload16(&sAh[(size_t)tid * 8],         &Ah[(size_t)(m0 + r0)      * K + k0 + c0 * 8]);
        gload16(&sAh[(size_t)(tid + 256) * 8], &Ah[(size_t)(m0 + r0 + 64) * K + k0 + c0 * 8]);
        gload16(&sAl[(size_t)tid * 8],         &Al[(size_t)(m0 + r0)      * K + k0 + c0 * 8]);
        gload16(&sAl[(size_t)(tid + 256) * 8], &Al[(size_t)(m0 + r0 + 64) * K + k0 + c0 * 8]);
        gload16(&sBh[(size_t)tid * 8],         &Bh[(size_t)(n0 + r0)      * K + k0 + c0 * 8]);
        gload16(&sBh[(size_t)(tid + 256) * 8], &Bh[(size_t)(n0 + r0 + 64) * K + k0 + c0 * 8]);
        gload16(&sBl[(size_t)tid * 8],         &Bl[(size_t)(n0 + r0)      * K + k0 + c0 * 8]);
        gload16(&sBl[(size_t)(tid + 256) * 8], &Bl[(size_t)(n0 + r0 + 64) * K + k0 + c0 * 8]);
        __syncthreads();   // compiler drains vmcnt before barrier

        bf16x8 ah[4], al[4], bh[4], bl[4];
        #pragma unroll
        for (int i = 0; i < 4; ++i) {
            ah[i] = *reinterpret_cast<const bf16x8*>(&sAh[(size_t)(rA + i * 16) * BK + co]);
            al[i] = *reinterpret_cast<const bf16x8*>(&sAl[(size_t)(rA + i * 16) * BK + co]);
        }
        #pragma unroll
        for (int j = 0; j < 4; ++j) {
            bh[j] = *reinterpret_cast<const bf16x8*>(&sBh[(size_t)(rB + j * 16) * BK + co]);
            bl[j] = *reinterpret_cast<const bf16x8*>(&sBl[(size_t)(rB + j * 16) * BK + co]);
        }
        #pragma unroll
        for (int i = 0; i < 4; ++i)
            #pragma unroll
            for (int j = 0; j < 4; ++j) {
                acc[i][j] = __builtin_amdgcn_mfma_f32_16x16x32_bf16(ah[i], bh[j], acc[i][j], 0, 0, 0);
                acc[i][j] = __builtin_amdgcn_mfma_f32_16x16x32_bf16(ah[i], bl[j], acc[i][j], 0, 0, 0);
                acc[i][j] = __builtin_amdgcn_mfma_f32_16x16x32_bf16(al[i], bh[j], acc[i][j], 0, 0, 0);
            }
        __syncthreads();
    }

    // C/D layout (m89-verified): col = lane&15, row = (lane>>4)*4 + reg
    float* Cz = Cp + (size_t)blockIdx.z * M * N;
    const int crow0 = m0 + wm + (lane >> 4) * 4;
    const int ccol0 = n0 + wn + (lane & 15);
    #pragma unroll
    for (int i = 0; i < 4; ++i)
        #pragma unroll
        for (int j = 0; j < 4; ++j)
            #pragma unroll
            for (int r = 0; r < 4; ++r)
                Cz[(size_t)(crow0 + i * 16 + r) * N + ccol0 + j * 16] = acc[i][j][r];
}

// ---------------------------------------------------------------------------
// reduce split-K partials: out = alpha * sum_z part[z] + bias. MN % 1024 == 0.
// ---------------------------------------------------------------------------
__global__ __launch_bounds__(256)
void reduce_kernel(const float* __restrict__ part, float* __restrict__ out,
                   const float* __restrict__ bias, int MN, int N, int Z, float alpha)
{
    const int i = (blockIdx.x * 256 + threadIdx.x) * 4;
    if (i >= MN) return;
    float4 s = *reinterpret_cast<const float4*>(&part[i]);
    for (int z = 1; z < Z; ++z) {
        float4 p = *reinterpret_cast<const float4*>(&part[(size_t)z * MN + i]);
        s.x += p.x; s.y += p.y; s.z += p.z; s.w += p.w;
    }
    s.x *= alpha; s.y *= alpha; s.z *= alpha; s.w *= alpha;
    if (bias) {
        const int c = i % N;
        s.x += bias[c]; s.y += bias[c + 1]; s.z += bias[c + 2]; s.w += bias[c + 3];
    }
    *reinterpret_cast<float4*>(&out[i]) = s;
}

// ---------------------------------------------------------------------------
// RoPE table: tab[t*64 + i] = cos(t*invfreq_i), tab[t*64+32+i] = sin(...)
// ---------------------------------------------------------------------------
__global__ __launch_bounds__(256)
void rope_table_kernel(float* __restrict__ tab)
{
    const int idx = blockIdx.x * 256 + threadIdx.x;   // 1024*32
    if (idx >= 32768) return;
    const int t = idx >> 5, i = idx & 31;
    const float inv = expf(-(float)i * (logf(10000.f) / 32.f));
    const float fr = (float)t * inv;
    tab[t * 64 + i]      = cosf(fr);
    tab[t * 64 + 32 + i] = sinf(fr);
}

// ---------------------------------------------------------------------------
// Fused wedge (x @ M[h], M[h] = I + (A - A^T) + diag(id_bias[h])) + RoPE.
// grid = (H_TOT, T/64), block = 256.
// outMode 0: Y[t*NQ + h*64 + c]  (in-place on Q buffer)
// outMode 1: Y[(h*T + t)*64 + c] (head-major K2)
// ---------------------------------------------------------------------------
__global__ __launch_bounds__(256)
void wedge_rope_kernel(const float* __restrict__ X, float* __restrict__ Y,
                       const float* __restrict__ Amat, const float* __restrict__ id_bias,
                       const float* __restrict__ tab,
                       int inStride, int inHeadMod, int outMode)
{
    const int h   = blockIdx.x;
    const int t0  = blockIdx.y * 64;
    const int tid = threadIdx.x;

    __shared__ float Ms[64][65];   // M[d][e]
    __shared__ float Xs[64][65];   // input tile (t_local, d)

    for (int idx = tid; idx < 4096; idx += 256) {
        const int d = idx >> 6, e = idx & 63;
        float v = Amat[d * 64 + e] - Amat[e * 64 + d];
        if (d == e) v += 1.0f + id_bias[h * 64 + d];
        Ms[d][e] = v;
    }
    const int cbase = (h % inHeadMod) * 64;
    for (int idx = tid; idx < 1024; idx += 256) {
        const int r  = idx >> 4;
        const int dq = (idx & 15) << 2;
        float4 v = *reinterpret_cast<const float4*>(&X[(size_t)(t0 + r) * inStride + cbase + dq]);
        Xs[r][dq + 0] = v.x; Xs[r][dq + 1] = v.y;
        Xs[r][dq + 2] = v.z; Xs[r][dq + 3] = v.w;
    }
    __syncthreads();

    const int r = tid >> 2;   // row 0..63
    const int q = tid & 3;    // channel quarter

    float y[16];
    #pragma unroll
    for (int ee = 0; ee < 16; ++ee) {
        const int e = q * 16 + ee;
        float accv = 0.f;
        #pragma unroll 8
        for (int d = 0; d < 64; ++d)
            accv = fmaf(Xs[r][d], Ms[d][e], accv);
        y[ee] = accv;
    }

    const int t = t0 + r;
    #pragma unroll
    for (int p = 0; p < 8; ++p) {
        const int i = q * 8 + p;           // 0..31
        const float cs = tab[t * 64 + i];
        const float sn = tab[t * 64 + 32 + i];
        const float x1 = y[2 * p];
        const float x2 = y[2 * p + 1];
        const float o1 = x1 * cs - x2 * sn;   // channel i
        const float o2 = x1 * sn + x2 * cs;   // channel 32+i
        if (outMode == 0) {
            Y[(size_t)t * NQ + h * 64 + i]      = o1;
            Y[(size_t)t * NQ + h * 64 + 32 + i] = o2;
        } else {
            Y[((size_t)h * T_SEQ + t) * 64 + i]      = o1;
            Y[((size_t)h * T_SEQ + t) * 64 + 32 + i] = o2;
        }
    }
}

// ---------------------------------------------------------------------------
// mean over branches of WO_b -> mbias[768]
// ---------------------------------------------------------------------------
__global__ void mean_bias_kernel(const float* __restrict__ WO_b, float* __restrict__ mb)
{
    const int d = blockIdx.x * 256 + threadIdx.x;
    if (d < C_MODEL) {
        float s = 0.f;
        #pragma unroll
        for (int n = 0; n < N_BR; ++n) s += WO_b[n * C_MODEL + d];
        mb[d] = s * (1.0f / 12.0f);
    }
}

// ---------------------------------------------------------------------------
// Flash attention with sink, fp32. grid = (H_TOT, T/64), block = 256.
// ---------------------------------------------------------------------------
__global__ __launch_bounds__(256)
void attn_kernel(float* QC,                         // Q in / ctx out (aliased)
                 const float* __restrict__ K2,
                 const float* __restrict__ Vb,
                 const float* __restrict__ sink,
                 const float* __restrict__ v_nulls)
{
    const int h   = blockIdx.x;     // 0..143
    const int qt  = blockIdx.y;     // 0..15
    const int s   = h % N_BR;
    const int tid = threadIdx.x;
    const int ty  = tid >> 4;       // 0..15
    const int tx  = tid & 15;       // 0..15

    __shared__ float Qs[64][65];
    __shared__ float KPs[64][65];   // K tile, reused as P
    __shared__ float Vs[64][64];

    for (int idx = tid; idx < 1024; idx += 256) {
        const int r  = idx >> 4;
        const int dq = (idx & 15) << 2;
        float4 v = *reinterpret_cast<const float4*>(&QC[(size_t)(qt * 64 + r) * NQ + h * 64 + dq]);
        Qs[r][dq + 0] = v.x; Qs[r][dq + 1] = v.y;
        Qs[r][dq + 2] = v.z; Qs[r][dq + 3] = v.w;
    }

    float acc[4][4] = {};
    float m_i[4], l_i[4];
    #pragma unroll
    for (int i = 0; i < 4; ++i) { m_i[i] = -__builtin_inff(); l_i[i] = 0.f; }

    __syncthreads();

    for (int kt = 0; kt <= qt; ++kt) {
        for (int idx = tid; idx < 1024; idx += 256) {
            const int r  = idx >> 4;
            const int dq = (idx & 15) << 2;
            float4 kv = *reinterpret_cast<const float4*>(&K2[((size_t)h * T_SEQ + kt * 64 + r) * 64 + dq]);
            KPs[r][dq + 0] = kv.x; KPs[r][dq + 1] = kv.y;
            KPs[r][dq + 2] = kv.z; KPs[r][dq + 3] = kv.w;
            float4 vv = *reinterpret_cast<const float4*>(&Vb[(size_t)(kt * 64 + r) * C_MODEL + s * 64 + dq]);
            Vs[r][dq + 0] = vv.x; Vs[r][dq + 1] = vv.y;
            Vs[r][dq + 2] = vv.z; Vs[r][dq + 3] = vv.w;
        }
        __syncthreads();

        float sv[4][4] = {};
        for (int d = 0; d < 64; ++d) {
            float qv[4], kv[4];
            #pragma unroll
            for (int i = 0; i < 4; ++i) qv[i] = Qs[4 * ty + i][d];
            #pragma unroll
            for (int j = 0; j < 4; ++j) kv[j] = KPs[4 * tx + j][d];
            #pragma unroll
            for (int i = 0; i < 4; ++i)
                #pragma unroll
                for (int j = 0; j < 4; ++j)
                    sv[i][j] = fmaf(qv[i], kv[j], sv[i][j]);
        }
        #pragma unroll
        for (int i = 0; i < 4; ++i)
            #pragma unroll
            for (int j = 0; j < 4; ++j) {
                sv[i][j] *= 0.125f;
                if (kt == qt && (4 * tx + j) > (4 * ty + i)) sv[i][j] = -__builtin_inff();
            }

        float scl[4];
        #pragma unroll
        for (int i = 0; i < 4; ++i) {
            float rm = fmaxf(fmaxf(sv[i][0], sv[i][1]), fmaxf(sv[i][2], sv[i][3]));
            #pragma unroll
            for (int w = 8; w >= 1; w >>= 1) rm = fmaxf(rm, __shfl_xor(rm, w));
            const float mn = fmaxf(m_i[i], rm);
            float rsum = 0.f;
            #pragma unroll
            for (int j = 0; j < 4; ++j) {
                sv[i][j] = __expf(sv[i][j] - mn);
                rsum += sv[i][j];
            }
            #pragma unroll
            for (int w = 8; w >= 1; w >>= 1) rsum += __shfl_xor(rsum, w);
            scl[i] = __expf(m_i[i] - mn);
            l_i[i] = l_i[i] * scl[i] + rsum;
            m_i[i] = mn;
        }

        __syncthreads();

        #pragma unroll
        for (int i = 0; i < 4; ++i)
            #pragma unroll
            for (int j = 0; j < 4; ++j)
                KPs[4 * ty + i][4 * tx + j] = sv[i][j];
        #pragma unroll
        for (int i = 0; i < 4; ++i)
            #pragma unroll
            for (int d = 0; d < 4; ++d)
                acc[i][d] *= scl[i];

        __syncthreads();

        for (int j = 0; j < 64; ++j) {
            float pv[4], vv[4];
            #pragma unroll
            for (int i = 0; i < 4; ++i) pv[i] = KPs[4 * ty + i][j];
            #pragma unroll
            for (int d = 0; d < 4; ++d) vv[d] = Vs[j][4 * tx + d];
            #pragma unroll
            for (int i = 0; i < 4; ++i)
                #pragma unroll
                for (int d = 0; d < 4; ++d)
                    acc[i][d] = fmaf(pv[i], vv[d], acc[i][d]);
        }
        __syncthreads();
    }

    const float snk = sink[h];
    #pragma unroll
    for (int i = 0; i < 4; ++i) {
        const float mt = fmaxf(m_i[i], snk);
        const float em = __expf(m_i[i] - mt);
        const float es = __expf(snk - mt);
        const float li = l_i[i] * em + es;
        const float oscale = em / li;
        const float psink  = es / li;
        const int trow = qt * 64 + 4 * ty + i;
        #pragma unroll
        for (int d = 0; d < 4; ++d) {
            const int col = 4 * tx + d;
            const float outv = acc[i][d] * oscale + psink * v_nulls[h * 64 + col];
            QC[(size_t)trow * NQ + h * 64 + col] = outv;
        }
    }
}

// ---------------------------------------------------------------------------
// launcher
// ---------------------------------------------------------------------------
extern "C" void kernel_launch(void* const* d_in, const int* in_sizes, int n_in,
                              void* d_out, int out_size, void* d_ws, size_t ws_size,
                              hipStream_t stream)
{
    (void)in_sizes; (void)n_in; (void)out_size; (void)ws_size;

    const float* x       = (const float*)d_in[0];
    const float* WV_w    = (const float*)d_in[1];
    const float* WV_b    = (const float*)d_in[2];
    const float* WK_w    = (const float*)d_in[3];
    const float* WK_b    = (const float*)d_in[4];
    const float* WQ_w    = (const float*)d_in[5];
    const float* Amat    = (const float*)d_in[6];
    const float* id_bias = (const float*)d_in[7];
    const float* sink    = (const float*)d_in[8];
    const float* v_nulls = (const float*)d_in[9];
    const float* WO_w    = (const float*)d_in[10];
    const float* WO_b    = (const float*)d_in[11];
    float* out = (float*)d_out;

    // workspace carve (floats / u16)
    float* ws    = (float*)d_ws;
    float* qbuf  = ws;                       // 9437184 f : Q -> ctx -> out-partials
    float* k2    = qbuf  + 9437184;          // 9437184 f : wedged K; later ctx hi/lo bf16
    float* kbase = k2    + 9437184;          // 786432 f
    float* vbase = kbase + 786432;           // 786432 f
    float* mbias = vbase + 786432;           // 768 f
    float* tab   = mbias + 768;              // 65536 f
    u16* xh  = (u16*)(tab + 65536);          // 786432 u16
    u16* xl  = xh  + 786432;
    u16* wkh = xl  + 786432;                 // 589824 u16
    u16* wkl = wkh + 589824;
    u16* wvh = wkl + 589824;
    u16* wvl = wvh + 589824;
    u16* wbh = wvl + 589824;                 // 7077888 u16 : WQt / KV-partials / WOt
    u16* wbl = wbh + 7077888;

    u16* ctxh = (u16*)k2;                    // ctx hi/lo overlay K2 after attention
    u16* ctxl = ctxh + 9437184;
    float* pkv = (float*)wbh;                // K/V split-K partials (12.6 MB < 28.3 MB)

    const dim3 blk(256);

    // rope table + input splits
    rope_table_kernel<<<dim3(128), blk, 0, stream>>>(tab);
    split_kernel<<<dim3(768), blk, 0, stream>>>(x, xh, xl, 786432);

    // Q projection: full-K, direct write
    split_t_kernel<<<dim3(288, 24), blk, 0, stream>>>(WQ_w, wbh, wbl, C_MODEL, NQ);
    gemm_split_kernel<<<dim3(72, 8, 1), blk, 0, stream>>>(
        xh, xl, wbh, wbl, qbuf, T_SEQ, NQ, C_MODEL);

    // K / V projections: split-K=4 + bias reduce
    split_t_kernel<<<dim3(24, 24), blk, 0, stream>>>(WK_w, wkh, wkl, C_MODEL, C_MODEL);
    split_t_kernel<<<dim3(24, 24), blk, 0, stream>>>(WV_w, wvh, wvl, C_MODEL, C_MODEL);
    gemm_split_kernel<<<dim3(6, 8, 4), blk, 0, stream>>>(
        xh, xl, wkh, wkl, pkv, T_SEQ, C_MODEL, C_MODEL);
    reduce_kernel<<<dim3(768), blk, 0, stream>>>(pkv, kbase, WK_b, 786432, C_MODEL, 4, 1.0f);
    gemm_split_kernel<<<dim3(6, 8, 4), blk, 0, stream>>>(
        xh, xl, wvh, wvl, pkv, T_SEQ, C_MODEL, C_MODEL);
    reduce_kernel<<<dim3(768), blk, 0, stream>>>(pkv, vbase, WV_b, 786432, C_MODEL, 4, 1.0f);

    // wedge + rope
    wedge_rope_kernel<<<dim3(H_TOT, 16), blk, 0, stream>>>(
        qbuf, qbuf, Amat, id_bias, tab, NQ, H_TOT, 0);
    wedge_rope_kernel<<<dim3(H_TOT, 16), blk, 0, stream>>>(
        kbase, k2, Amat, id_bias, tab, C_MODEL, N_BR, 1);

    mean_bias_kernel<<<dim3(3), blk, 0, stream>>>(WO_b, mbias);

    // attention (ctx in-place over Q)
    attn_kernel<<<dim3(H_TOT, 16), blk, 0, stream>>>(qbuf, k2, vbase, sink, v_nulls);

    // output projection: split ctx, transpose-split WO, split-K=12 GEMM, reduce
    split_kernel<<<dim3(9216), blk, 0, stream>>>(qbuf, ctxh, ctxl, 9437184);
    split_t_kernel<<<dim3(24, 288), blk, 0, stream>>>(WO_w, wbh, wbl, NQ, C_MODEL);
    gemm_split_kernel<<<dim3(6, 8, 12), blk, 0, stream>>>(
        ctxh, ctxl, wbh, wbl, qbuf, T_SEQ, C_MODEL, NQ);
    reduce_kernel<<<dim3(768), blk, 0, stream>>>(qbuf, out, mbias, 786432, C_MODEL, 12, 1.0f / 12.0f);
}

// Round 3
// 285.304 us; speedup vs baseline: 5.7896x; 2.9785x over previous
//
#include <hip/hip_runtime.h>
#include <hip/hip_bf16.h>

// Problem constants (B=1)
#define T_SEQ   1024
#define C_MODEL 768
#define N_BR    12
#define DH      64
#define H_TOT   144          // N_BR * N_BR
#define NQ      9216         // C_MODEL * N_BR

typedef __bf16 bf16x8 __attribute__((ext_vector_type(8)));
typedef float  f32x4  __attribute__((ext_vector_type(4)));
typedef unsigned short u16;

// ---------------------------------------------------------------------------
// helpers
// ---------------------------------------------------------------------------
__device__ __forceinline__ void gload16(void* lds, const void* g)
{
    __builtin_amdgcn_global_load_lds(
        (const __attribute__((address_space(1))) void*)g,
        (__attribute__((address_space(3))) void*)lds, 16, 0, 0);
}

__device__ __forceinline__ void split1(float x, u16& h, u16& l)
{
    __bf16 bh = (__bf16)x;
    __bf16 bl = (__bf16)(x - (float)bh);
    h = __builtin_bit_cast(u16, bh);
    l = __builtin_bit_cast(u16, bl);
}

__device__ __forceinline__ u16 tobf(float x)
{
    return __builtin_bit_cast(u16, (__bf16)x);
}

// swizzled LDS byte address for 128B-row tiles: spreads 16 rows over 8 bank-groups
__device__ __forceinline__ int swb(int row, int byteoff)
{
    return row * 128 + (byteoff ^ ((row & 7) << 4));
}

__device__ __forceinline__ bf16x8 ldsr8(const u16* p, int byteoff)
{
    return *reinterpret_cast<const bf16x8*>(reinterpret_cast<const char*>(p) + byteoff);
}

// ---------------------------------------------------------------------------
// elementwise fp32 -> (hi, lo) bf16 split
// ---------------------------------------------------------------------------
__global__ __launch_bounds__(256)
void split_kernel(const float* __restrict__ in, u16* __restrict__ hi,
                  u16* __restrict__ lo, int n)
{
    const int i = (blockIdx.x * 256 + threadIdx.x) * 4;
    if (i >= n) return;
    float4 v = *reinterpret_cast<const float4*>(&in[i]);
    u16 h0,h1,h2,h3,l0,l1,l2,l3;
    split1(v.x,h0,l0); split1(v.y,h1,l1); split1(v.z,h2,l2); split1(v.w,h3,l3);
    hi[i+0]=h0; hi[i+1]=h1; hi[i+2]=h2; hi[i+3]=h3;
    lo[i+0]=l0; lo[i+1]=l1; lo[i+2]=l2; lo[i+3]=l3;
}

// ---------------------------------------------------------------------------
// transpose + split: W[K][N] fp32 -> Wt_hi/lo[N][K] bf16
// ---------------------------------------------------------------------------
__global__ __launch_bounds__(256)
void split_t_kernel(const float* __restrict__ W, u16* __restrict__ hi,
                    u16* __restrict__ lo, int K, int N)
{
    __shared__ float t[32][33];
    const int n0 = blockIdx.x * 32;
    const int k0 = blockIdx.y * 32;
    const int tx = threadIdx.x & 31;
    const int ty = threadIdx.x >> 5;      // 0..7
    #pragma unroll
    for (int r = 0; r < 4; ++r)
        t[ty + r * 8][tx] = W[(size_t)(k0 + ty + r * 8) * N + n0 + tx];
    __syncthreads();
    #pragma unroll
    for (int r = 0; r < 4; ++r) {
        const float v = t[tx][ty + r * 8];
        u16 h, l;
        split1(v, h, l);
        const size_t o = (size_t)(n0 + ty + r * 8) * K + k0 + tx;
        hi[o] = h; lo[o] = l;
    }
}

// transpose, single bf16: W[K][N] fp32 -> Wt[N][K] bf16
__global__ __launch_bounds__(256)
void convt_kernel(const float* __restrict__ W, u16* __restrict__ out, int K, int N)
{
    __shared__ float t[32][33];
    const int n0 = blockIdx.x * 32;
    const int k0 = blockIdx.y * 32;
    const int tx = threadIdx.x & 31;
    const int ty = threadIdx.x >> 5;
    #pragma unroll
    for (int r = 0; r < 4; ++r)
        t[ty + r * 8][tx] = W[(size_t)(k0 + ty + r * 8) * N + n0 + tx];
    __syncthreads();
    #pragma unroll
    for (int r = 0; r < 4; ++r)
        out[(size_t)(n0 + ty + r * 8) * K + k0 + tx] = tobf(t[tx][ty + r * 8]);
}

// ---------------------------------------------------------------------------
// Split-bf16 MFMA GEMM (NT), 128x128 tile, BK=32, m97 structure.
// ---------------------------------------------------------------------------
#define BM 128
#define BN 128
#define BK 32

__global__ __launch_bounds__(256)
void gemm_split_kernel(const u16* __restrict__ Ah, const u16* __restrict__ Al,
                       const u16* __restrict__ Bh, const u16* __restrict__ Bl,
                       float* __restrict__ Cp, int M, int N, int K)
{
    __shared__ __align__(16) u16 sAh[BM * BK], sAl[BM * BK], sBh[BN * BK], sBl[BN * BK];

    const int tid  = threadIdx.x;
    const int lane = tid & 63;
    const int wid  = tid >> 6;
    const int m0   = blockIdx.y * BM;
    const int n0   = blockIdx.x * BN;
    const int kc   = K / gridDim.z;
    const int kbeg = blockIdx.z * kc;
    const int kend = kbeg + kc;

    const int wm = (wid >> 1) * 64;
    const int wn = (wid & 1) * 64;

    f32x4 acc[4][4];
    #pragma unroll
    for (int i = 0; i < 4; ++i)
        #pragma unroll
        for (int j = 0; j < 4; ++j)
            #pragma unroll
            for (int r = 0; r < 4; ++r) acc[i][j][r] = 0.f;

    const int r0 = tid >> 2;       // 0..63
    const int c0 = tid & 3;        // k offset c0*8

    const int rA = wm + (lane & 15);
    const int rB = wn + (lane & 15);
    const int co = (lane >> 4) * 8;

    for (int k0 = kbeg; k0 < kend; k0 += BK) {
        gload16(&sAh[(size_t)tid * 8],         &Ah[(size_t)(m0 + r0)      * K + k0 + c0 * 8]);
        gload16(&sAh[(size_t)(tid + 256) * 8], &Ah[(size_t)(m0 + r0 + 64) * K + k0 + c0 * 8]);
        gload16(&sAl[(size_t)tid * 8],         &Al[(size_t)(m0 + r0)      * K + k0 + c0 * 8]);
        gload16(&sAl[(size_t)(tid + 256) * 8], &Al[(size_t)(m0 + r0 + 64) * K + k0 + c0 * 8]);
        gload16(&sBh[(size_t)tid * 8],         &Bh[(size_t)(n0 + r0)      * K + k0 + c0 * 8]);
        gload16(&sBh[(size_t)(tid + 256) * 8], &Bh[(size_t)(n0 + r0 + 64) * K + k0 + c0 * 8]);
        gload16(&sBl[(size_t)tid * 8],         &Bl[(size_t)(n0 + r0)      * K + k0 + c0 * 8]);
        gload16(&sBl[(size_t)(tid + 256) * 8], &Bl[(size_t)(n0 + r0 + 64) * K + k0 + c0 * 8]);
        __syncthreads();

        bf16x8 ah[4], al[4], bh[4], bl[4];
        #pragma unroll
        for (int i = 0; i < 4; ++i) {
            ah[i] = *reinterpret_cast<const bf16x8*>(&sAh[(size_t)(rA + i * 16) * BK + co]);
            al[i] = *reinterpret_cast<const bf16x8*>(&sAl[(size_t)(rA + i * 16) * BK + co]);
        }
        #pragma unroll
        for (int j = 0; j < 4; ++j) {
            bh[j] = *reinterpret_cast<const bf16x8*>(&sBh[(size_t)(rB + j * 16) * BK + co]);
            bl[j] = *reinterpret_cast<const bf16x8*>(&sBl[(size_t)(rB + j * 16) * BK + co]);
        }
        #pragma unroll
        for (int i = 0; i < 4; ++i)
            #pragma unroll
            for (int j = 0; j < 4; ++j) {
                acc[i][j] = __builtin_amdgcn_mfma_f32_16x16x32_bf16(ah[i], bh[j], acc[i][j], 0, 0, 0);
                acc[i][j] = __builtin_amdgcn_mfma_f32_16x16x32_bf16(ah[i], bl[j], acc[i][j], 0, 0, 0);
                acc[i][j] = __builtin_amdgcn_mfma_f32_16x16x32_bf16(al[i], bh[j], acc[i][j], 0, 0, 0);
            }
        __syncthreads();
    }

    float* Cz = Cp + (size_t)blockIdx.z * M * N;
    const int crow0 = m0 + wm + (lane >> 4) * 4;
    const int ccol0 = n0 + wn + (lane & 15);
    #pragma unroll
    for (int i = 0; i < 4; ++i)
        #pragma unroll
        for (int j = 0; j < 4; ++j)
            #pragma unroll
            for (int r = 0; r < 4; ++r)
                Cz[(size_t)(crow0 + i * 16 + r) * N + ccol0 + j * 16] = acc[i][j][r];
}

// plain-bf16 MFMA GEMM (NT), same structure, 1 MFMA per step
__global__ __launch_bounds__(256)
void gemm_bf16_kernel(const u16* __restrict__ A, const u16* __restrict__ B,
                      float* __restrict__ Cp, int M, int N, int K)
{
    __shared__ __align__(16) u16 sA[BM * BK], sB[BN * BK];

    const int tid  = threadIdx.x;
    const int lane = tid & 63;
    const int wid  = tid >> 6;
    const int m0   = blockIdx.y * BM;
    const int n0   = blockIdx.x * BN;
    const int kc   = K / gridDim.z;
    const int kbeg = blockIdx.z * kc;
    const int kend = kbeg + kc;

    const int wm = (wid >> 1) * 64;
    const int wn = (wid & 1) * 64;

    f32x4 acc[4][4];
    #pragma unroll
    for (int i = 0; i < 4; ++i)
        #pragma unroll
        for (int j = 0; j < 4; ++j)
            #pragma unroll
            for (int r = 0; r < 4; ++r) acc[i][j][r] = 0.f;

    const int r0 = tid >> 2;
    const int c0 = tid & 3;
    const int rA = wm + (lane & 15);
    const int rB = wn + (lane & 15);
    const int co = (lane >> 4) * 8;

    for (int k0 = kbeg; k0 < kend; k0 += BK) {
        gload16(&sA[(size_t)tid * 8],         &A[(size_t)(m0 + r0)      * K + k0 + c0 * 8]);
        gload16(&sA[(size_t)(tid + 256) * 8], &A[(size_t)(m0 + r0 + 64) * K + k0 + c0 * 8]);
        gload16(&sB[(size_t)tid * 8],         &B[(size_t)(n0 + r0)      * K + k0 + c0 * 8]);
        gload16(&sB[(size_t)(tid + 256) * 8], &B[(size_t)(n0 + r0 + 64) * K + k0 + c0 * 8]);
        __syncthreads();

        bf16x8 ah[4], bh[4];
        #pragma unroll
        for (int i = 0; i < 4; ++i)
            ah[i] = *reinterpret_cast<const bf16x8*>(&sA[(size_t)(rA + i * 16) * BK + co]);
        #pragma unroll
        for (int j = 0; j < 4; ++j)
            bh[j] = *reinterpret_cast<const bf16x8*>(&sB[(size_t)(rB + j * 16) * BK + co]);
        #pragma unroll
        for (int i = 0; i < 4; ++i)
            #pragma unroll
            for (int j = 0; j < 4; ++j)
                acc[i][j] = __builtin_amdgcn_mfma_f32_16x16x32_bf16(ah[i], bh[j], acc[i][j], 0, 0, 0);
        __syncthreads();
    }

    float* Cz = Cp + (size_t)blockIdx.z * M * N;
    const int crow0 = m0 + wm + (lane >> 4) * 4;
    const int ccol0 = n0 + wn + (lane & 15);
    #pragma unroll
    for (int i = 0; i < 4; ++i)
        #pragma unroll
        for (int j = 0; j < 4; ++j)
            #pragma unroll
            for (int r = 0; r < 4; ++r)
                Cz[(size_t)(crow0 + i * 16 + r) * N + ccol0 + j * 16] = acc[i][j][r];
}

// ---------------------------------------------------------------------------
// reduce split-K partials
// ---------------------------------------------------------------------------
__global__ __launch_bounds__(256)
void reduce_kernel(const float* __restrict__ part, float* __restrict__ out,
                   const float* __restrict__ bias, int MN, int N, int Z, float alpha)
{
    const int i = (blockIdx.x * 256 + threadIdx.x) * 4;
    if (i >= MN) return;
    float4 s = *reinterpret_cast<const float4*>(&part[i]);
    for (int z = 1; z < Z; ++z) {
        float4 p = *reinterpret_cast<const float4*>(&part[(size_t)z * MN + i]);
        s.x += p.x; s.y += p.y; s.z += p.z; s.w += p.w;
    }
    s.x *= alpha; s.y *= alpha; s.z *= alpha; s.w *= alpha;
    if (bias) {
        const int c = i % N;
        s.x += bias[c]; s.y += bias[c + 1]; s.z += bias[c + 2]; s.w += bias[c + 3];
    }
    *reinterpret_cast<float4*>(&out[i]) = s;
}

// ---------------------------------------------------------------------------
// RoPE table
// ---------------------------------------------------------------------------
__global__ __launch_bounds__(256)
void rope_table_kernel(float* __restrict__ tab)
{
    const int idx = blockIdx.x * 256 + threadIdx.x;
    if (idx >= 32768) return;
    const int t = idx >> 5, i = idx & 31;
    const float inv = expf(-(float)i * (logf(10000.f) / 32.f));
    const float fr = (float)t * inv;
    tab[t * 64 + i]      = cosf(fr);
    tab[t * 64 + 32 + i] = sinf(fr);
}

// ---------------------------------------------------------------------------
// build per-head M^T (hi/lo bf16): Mt[h][e][d] = A[d][e]-A[e][d] + (d==e)(1+b)
// ---------------------------------------------------------------------------
__global__ __launch_bounds__(256)
void build_m_kernel(const float* __restrict__ Amat, const float* __restrict__ id_bias,
                    u16* __restrict__ Mth, u16* __restrict__ Mtl)
{
    const int h = blockIdx.x;
    const int base = threadIdx.x * 16;
    #pragma unroll
    for (int i = 0; i < 16; ++i) {
        const int idx = base + i;
        const int e = idx >> 6, d = idx & 63;
        float v = Amat[d * 64 + e] - Amat[e * 64 + d];
        if (d == e) v += 1.0f + id_bias[h * 64 + d];
        u16 hh, ll;
        split1(v, hh, ll);
        Mth[(size_t)h * 4096 + idx] = hh;
        Mtl[(size_t)h * 4096 + idx] = ll;
    }
}

// ---------------------------------------------------------------------------
// MFMA wedge + rope: Y_bf16[h][t][d] = rope(X_tile @ M[h]) * scale
// grid = (H_TOT, T/64), block = 256 (4 waves).
// ---------------------------------------------------------------------------
__global__ __launch_bounds__(256)
void wedge_mfma_kernel(const float* __restrict__ X, u16* __restrict__ Y,
                       const u16* __restrict__ Mth, const u16* __restrict__ Mtl,
                       const float* __restrict__ tab,
                       int inStride, int headMod, float scale)
{
    const int h   = blockIdx.x;
    const int t0  = blockIdx.y * 64;
    const int tid = threadIdx.x;
    const int lane = tid & 63;
    const int w    = tid >> 6;
    const int g    = lane >> 4;
    const int li   = lane & 15;

    __shared__ __align__(16) u16 sXh[4096], sXl[4096], sMh[4096], sMl[4096];

    // stage X tile (reg-staged, swizzled write)
    {
        const int r  = tid >> 2;
        const int c0 = (tid & 3) * 16;
        const float* xrow = X + (size_t)(t0 + r) * inStride + (h % headMod) * 64;
        #pragma unroll
        for (int q = 0; q < 4; ++q) {
            const int c = c0 + q * 4;
            float4 v = *reinterpret_cast<const float4*>(&xrow[c]);
            u16 h0,h1,h2,h3,l0,l1,l2,l3;
            split1(v.x,h0,l0); split1(v.y,h1,l1); split1(v.z,h2,l2); split1(v.w,h3,l3);
            ushort4 hv = {h0,h1,h2,h3}, lv = {l0,l1,l2,l3};
            const int byte = swb(r, 2 * c);
            *reinterpret_cast<ushort4*>(reinterpret_cast<char*>(sXh) + byte) = hv;
            *reinterpret_cast<ushort4*>(reinterpret_cast<char*>(sXl) + byte) = lv;
        }
    }
    // stage M tiles via global_load_lds with inverse-swizzled source
    {
        const char* gmh = (const char*)(Mth + (size_t)h * 4096);
        const char* gml = (const char*)(Mtl + (size_t)h * 4096);
        #pragma unroll
        for (int u = 0; u < 2; ++u) {
            const int L = (u * 256 + tid) * 16;
            const int row = L >> 7, off = L & 127;
            const int src = swb(row, off);
            gload16(reinterpret_cast<char*>(sMh) + L, gmh + src);
            gload16(reinterpret_cast<char*>(sMl) + L, gml + src);
        }
    }
    __syncthreads();

    f32x4 acc[4];
    #pragma unroll
    for (int j = 0; j < 4; ++j)
        #pragma unroll
        for (int r = 0; r < 4; ++r) acc[j][r] = 0.f;

    bf16x8 ah[2], al[2];
    #pragma unroll
    for (int ks = 0; ks < 2; ++ks) {
        const int row = w * 16 + li;
        const int off = ks * 64 + g * 16;
        ah[ks] = ldsr8(sXh, swb(row, off));
        al[ks] = ldsr8(sXl, swb(row, off));
    }
    #pragma unroll
    for (int ks = 0; ks < 2; ++ks)
        #pragma unroll
        for (int j = 0; j < 4; ++j) {
            const int row = 16 * j + li;
            const int off = ks * 64 + g * 16;
            bf16x8 bh = ldsr8(sMh, swb(row, off));
            bf16x8 bl = ldsr8(sMl, swb(row, off));
            acc[j] = __builtin_amdgcn_mfma_f32_16x16x32_bf16(ah[ks], bh, acc[j], 0, 0, 0);
            acc[j] = __builtin_amdgcn_mfma_f32_16x16x32_bf16(ah[ks], bl, acc[j], 0, 0, 0);
            acc[j] = __builtin_amdgcn_mfma_f32_16x16x32_bf16(al[ks], bh, acc[j], 0, 0, 0);
        }

    // rope epilogue: C/D layout col = 16j+li, row = g*4+r (+ w*16)
    const bool ev = (li & 1) == 0;
    #pragma unroll
    for (int j = 0; j < 4; ++j) {
        const int e = 16 * j + li;
        const int i2 = e >> 1;
        #pragma unroll
        for (int r = 0; r < 4; ++r) {
            const int t = t0 + w * 16 + g * 4 + r;
            const float own = acc[j][r];
            const float oth = __shfl_xor(own, 1);
            const float cs = tab[t * 64 + i2];
            const float sn = tab[t * 64 + 32 + i2];
            float o; int ch;
            if (ev) { o = own * cs - oth * sn; ch = i2; }        // x1*cs - x2*sn
            else    { o = oth * sn + own * cs; ch = 32 + i2; }   // x1*sn + x2*cs
            Y[((size_t)h * T_SEQ + t) * 64 + ch] = tobf(o * scale);
        }
    }
}

// ---------------------------------------------------------------------------
// transpose V: vbase[t][768] slice s -> Vt[s][d][t] bf16
// grid = (12, 16), block 256.
// ---------------------------------------------------------------------------
__global__ __launch_bounds__(256)
void vt_kernel(const float* __restrict__ vbase, u16* __restrict__ Vt)
{
    __shared__ float Ls[64][65];
    const int s  = blockIdx.x;
    const int t0 = blockIdx.y * 64;
    const int tid = threadIdx.x;
    {
        const int r  = tid >> 2;
        const int c0 = (tid & 3) * 16;
        const float* row = vbase + (size_t)(t0 + r) * C_MODEL + s * 64;
        #pragma unroll
        for (int q = 0; q < 4; ++q) {
            float4 v = *reinterpret_cast<const float4*>(&row[c0 + q * 4]);
            Ls[r][c0 + q * 4 + 0] = v.x; Ls[r][c0 + q * 4 + 1] = v.y;
            Ls[r][c0 + q * 4 + 2] = v.z; Ls[r][c0 + q * 4 + 3] = v.w;
        }
    }
    __syncthreads();
    {
        const int d  = tid >> 2;
        const int tq = (tid & 3) * 16;
        u16* orow = Vt + ((size_t)s * 64 + d) * T_SEQ + t0 + tq;
        #pragma unroll
        for (int q = 0; q < 4; ++q) {
            ushort4 o;
            o.x = tobf(Ls[tq + q * 4 + 0][d]);
            o.y = tobf(Ls[tq + q * 4 + 1][d]);
            o.z = tobf(Ls[tq + q * 4 + 2][d]);
            o.w = tobf(Ls[tq + q * 4 + 3][d]);
            *reinterpret_cast<ushort4*>(&orow[q * 4]) = o;
        }
    }
}

// ---------------------------------------------------------------------------
// mean over branches of WO_b
// ---------------------------------------------------------------------------
__global__ void mean_bias_kernel(const float* __restrict__ WO_b, float* __restrict__ mb)
{
    const int d = blockIdx.x * 256 + threadIdx.x;
    if (d < C_MODEL) {
        float s = 0.f;
        #pragma unroll
        for (int n = 0; n < N_BR; ++n) s += WO_b[n * C_MODEL + d];
        mb[d] = s * (1.0f / 12.0f);
    }
}

// ---------------------------------------------------------------------------
// MFMA flash attention with sink. grid = (H_TOT, 16), block 256 (4 waves).
// Q2[h][t][d] bf16 (pre-scaled by 0.125), K2[h][t][d] bf16, Vt[s][d][t] bf16.
// Writes ctx bf16 [t][h*64+d].
// ---------------------------------------------------------------------------
__global__ __launch_bounds__(256)
void attn_mfma_kernel(const u16* __restrict__ Q2, const u16* __restrict__ K2,
                      const u16* __restrict__ Vt, const float* __restrict__ sink,
                      const float* __restrict__ v_nulls, u16* __restrict__ ctxb)
{
    const int h  = blockIdx.x;
    const int qt = 15 - blockIdx.y;        // heavy tiles first
    const int s  = h % N_BR;
    const int tid  = threadIdx.x;
    const int lane = tid & 63;
    const int w    = tid >> 6;
    const int g    = lane >> 4;
    const int li   = lane & 15;

    __shared__ __align__(16) u16 sQ[4096], sK[4096], sV[4096], sP[4096];

    // stage Q (once)
    {
        const char* gq = (const char*)(Q2 + ((size_t)h * T_SEQ + qt * 64) * 64);
        #pragma unroll
        for (int u = 0; u < 2; ++u) {
            const int L = (u * 256 + tid) * 16;
            const int row = L >> 7, off = L & 127;
            gload16(reinterpret_cast<char*>(sQ) + L, gq + swb(row, off));
        }
    }

    f32x4 acc[4];
    #pragma unroll
    for (int j = 0; j < 4; ++j)
        #pragma unroll
        for (int r = 0; r < 4; ++r) acc[j][r] = 0.f;
    float m_i[4], l_i[4];
    #pragma unroll
    for (int r = 0; r < 4; ++r) { m_i[r] = -__builtin_inff(); l_i[r] = 0.f; }

    for (int kt = 0; kt <= qt; ++kt) {
        // stage K tile and V^T tile
        {
            const char* gk = (const char*)(K2 + ((size_t)h * T_SEQ + kt * 64) * 64);
            const char* gv = (const char*)Vt + (size_t)s * 64 * 2048 + kt * 128;
            #pragma unroll
            for (int u = 0; u < 2; ++u) {
                const int L = (u * 256 + tid) * 16;
                const int row = L >> 7, off = L & 127;
                gload16(reinterpret_cast<char*>(sK) + L, gk + swb(row, off));
                const int srcv = row * 2048 + (off ^ ((row & 7) << 4));
                gload16(reinterpret_cast<char*>(sV) + L, gv + srcv);
            }
        }
        __syncthreads();

        // S = Q K^T (scale pre-folded into Q)
        f32x4 sacc[4];
        #pragma unroll
        for (int j = 0; j < 4; ++j)
            #pragma unroll
            for (int r = 0; r < 4; ++r) sacc[j][r] = 0.f;

        bf16x8 qa[2];
        #pragma unroll
        for (int ks = 0; ks < 2; ++ks)
            qa[ks] = ldsr8(sQ, swb(w * 16 + li, ks * 64 + g * 16));
        #pragma unroll
        for (int ks = 0; ks < 2; ++ks)
            #pragma unroll
            for (int j = 0; j < 4; ++j) {
                bf16x8 kb = ldsr8(sK, swb(16 * j + li, ks * 64 + g * 16));
                sacc[j] = __builtin_amdgcn_mfma_f32_16x16x32_bf16(qa[ks], kb, sacc[j], 0, 0, 0);
            }

        // online softmax (rows = w*16 + g*4 + r; cols = 16j + li)
        const int rowb = w * 16 + g * 4;
        float scl[4];
        #pragma unroll
        for (int r = 0; r < 4; ++r) {
            float mx = -__builtin_inff();
            #pragma unroll
            for (int j = 0; j < 4; ++j) {
                float v = sacc[j][r];
                if (kt == qt && (16 * j + li) > (rowb + r)) v = -__builtin_inff();
                sacc[j][r] = v;
                mx = fmaxf(mx, v);
            }
            #pragma unroll
            for (int d = 8; d >= 1; d >>= 1) mx = fmaxf(mx, __shfl_xor(mx, d));
            const float mn = fmaxf(m_i[r], mx);
            float rsum = 0.f;
            #pragma unroll
            for (int j = 0; j < 4; ++j) {
                const float p = __expf(sacc[j][r] - mn);
                sacc[j][r] = p;
                rsum += p;
            }
            #pragma unroll
            for (int d = 8; d >= 1; d >>= 1) rsum += __shfl_xor(rsum, d);
            scl[r] = __expf(m_i[r] - mn);
            l_i[r] = l_i[r] * scl[r] + rsum;
            m_i[r] = mn;
        }
        #pragma unroll
        for (int j = 0; j < 4; ++j)
            #pragma unroll
            for (int r = 0; r < 4; ++r) acc[j][r] *= scl[r];

        // write P (wave-private LDS region, swizzled)
        char* pbase = reinterpret_cast<char*>(sP) + w * 2048;
        #pragma unroll
        for (int j = 0; j < 4; ++j)
            #pragma unroll
            for (int r = 0; r < 4; ++r) {
                const int prow = g * 4 + r;
                const int byte = prow * 128 + ((2 * (16 * j + li)) ^ ((prow & 7) << 4));
                *reinterpret_cast<u16*>(pbase + byte) = tobf(sacc[j][r]);
            }

        // PV: acc += P @ V   (A = P rows li, B = V^T rows d)
        bf16x8 pa[2];
        #pragma unroll
        for (int ks = 0; ks < 2; ++ks)
            pa[ks] = *reinterpret_cast<const bf16x8*>(
                pbase + li * 128 + ((ks * 64 + g * 16) ^ ((li & 7) << 4)));
        #pragma unroll
        for (int ks = 0; ks < 2; ++ks)
            #pragma unroll
            for (int j = 0; j < 4; ++j) {
                bf16x8 vb = ldsr8(sV, swb(16 * j + li, ks * 64 + g * 16));
                acc[j] = __builtin_amdgcn_mfma_f32_16x16x32_bf16(pa[ks], vb, acc[j], 0, 0, 0);
            }
        __syncthreads();
    }

    // finalize: sink merge, normalize, add sink*v_nulls, store bf16 ctx
    const float snk = sink[h];
    #pragma unroll
    for (int r = 0; r < 4; ++r) {
        const float mt = fmaxf(m_i[r], snk);
        const float em = __expf(m_i[r] - mt);
        const float es = __expf(snk - mt);
        const float li_ = l_i[r] * em + es;
        const float oscale = em / li_;
        const float psink  = es / li_;
        const int trow = qt * 64 + w * 16 + g * 4 + r;
        #pragma unroll
        for (int j = 0; j < 4; ++j) {
            const int col = 16 * j + li;
            const float outv = acc[j][r] * oscale + psink * v_nulls[h * 64 + col];
            ctxb[(size_t)trow * NQ + h * 64 + col] = tobf(outv);
        }
    }
}

// ---------------------------------------------------------------------------
// launcher
// ---------------------------------------------------------------------------
extern "C" void kernel_launch(void* const* d_in, const int* in_sizes, int n_in,
                              void* d_out, int out_size, void* d_ws, size_t ws_size,
                              hipStream_t stream)
{
    (void)in_sizes; (void)n_in; (void)out_size; (void)ws_size;

    const float* x       = (const float*)d_in[0];
    const float* WV_w    = (const float*)d_in[1];
    const float* WV_b    = (const float*)d_in[2];
    const float* WK_w    = (const float*)d_in[3];
    const float* WK_b    = (const float*)d_in[4];
    const float* WQ_w    = (const float*)d_in[5];
    const float* Amat    = (const float*)d_in[6];
    const float* id_bias = (const float*)d_in[7];
    const float* sink    = (const float*)d_in[8];
    const float* v_nulls = (const float*)d_in[9];
    const float* WO_w    = (const float*)d_in[10];
    const float* WO_b    = (const float*)d_in[11];
    float* out = (float*)d_out;

    // ---- workspace carve ----
    float* ws    = (float*)d_ws;
    float* qbuf  = ws;                       // 9437184 f  (Q fp32; later ctx bf16 overlay)
    float* kbase = qbuf + 9437184;           // 786432 f
    float* vbase = kbase + 786432;           // 786432 f
    float* mbias = vbase + 786432;           // 768 f
    float* tab   = mbias + 768;              // 65536 f
    u16* xh  = (u16*)(tab + 65536);          // 786432
    u16* xl  = xh + 786432;
    u16* wkh = xl + 786432;                  // 589824 each
    u16* wkl = wkh + 589824;
    u16* wvh = wkl + 589824;
    u16* wvl = wvh + 589824;
    u16* wqh = wvl + 589824;                 // 7077888 each (aliased: pkv, wot)
    u16* wql = wqh + 7077888;
    u16* Mth = wql + 7077888;                // 589824 each
    u16* Mtl = Mth + 589824;
    u16* Q2  = Mtl + 589824;                 // 9437184
    u16* K2  = Q2 + 9437184;                 // 9437184 (later: out-proj partials f32 Z=6)
    u16* Vt  = K2 + 9437184;                 // 786432

    u16*   ctxb    = (u16*)qbuf;             // ctx bf16 (qbuf dead after wedge-Q)
    float* pkv     = (float*)wqh;            // K/V split-K partials (12.6 MB)
    u16*   wot     = wqh;                    // WO^T bf16 (after pkv dead)
    float* outpart = (float*)K2;             // out-proj partials, 6*786432 f = K2 size

    const dim3 blk(256);

    // tables + input split
    rope_table_kernel<<<dim3(128), blk, 0, stream>>>(tab);
    split_kernel<<<dim3(768), blk, 0, stream>>>(x, xh, xl, 786432);
    build_m_kernel<<<dim3(H_TOT), blk, 0, stream>>>(Amat, id_bias, Mth, Mtl);
    mean_bias_kernel<<<dim3(3), blk, 0, stream>>>(WO_b, mbias);

    // Q projection (hi/lo): qbuf = x @ WQ
    split_t_kernel<<<dim3(288, 24), blk, 0, stream>>>(WQ_w, wqh, wql, C_MODEL, NQ);
    gemm_split_kernel<<<dim3(72, 8, 1), blk, 0, stream>>>(
        xh, xl, wqh, wql, qbuf, T_SEQ, NQ, C_MODEL);

    // K / V projections (hi/lo, split-K=4), partials alias wq region
    split_t_kernel<<<dim3(24, 24), blk, 0, stream>>>(WK_w, wkh, wkl, C_MODEL, C_MODEL);
    split_t_kernel<<<dim3(24, 24), blk, 0, stream>>>(WV_w, wvh, wvl, C_MODEL, C_MODEL);
    gemm_split_kernel<<<dim3(6, 8, 4), blk, 0, stream>>>(
        xh, xl, wkh, wkl, pkv, T_SEQ, C_MODEL, C_MODEL);
    reduce_kernel<<<dim3(768), blk, 0, stream>>>(pkv, kbase, WK_b, 786432, C_MODEL, 4, 1.0f);
    gemm_split_kernel<<<dim3(6, 8, 4), blk, 0, stream>>>(
        xh, xl, wvh, wvl, pkv, T_SEQ, C_MODEL, C_MODEL);
    reduce_kernel<<<dim3(768), blk, 0, stream>>>(pkv, vbase, WV_b, 786432, C_MODEL, 4, 1.0f);

    // wedge + rope -> bf16 head-major (Q pre-scaled by dh^-0.5)
    wedge_mfma_kernel<<<dim3(H_TOT, 16), blk, 0, stream>>>(
        qbuf, Q2, Mth, Mtl, tab, NQ, H_TOT, 0.125f);
    wedge_mfma_kernel<<<dim3(H_TOT, 16), blk, 0, stream>>>(
        kbase, K2, Mth, Mtl, tab, C_MODEL, N_BR, 1.0f);

    // V transpose -> bf16 [s][d][t]
    vt_kernel<<<dim3(12, 16), blk, 0, stream>>>(vbase, Vt);

    // MFMA flash attention -> ctx bf16 (over qbuf region)
    attn_mfma_kernel<<<dim3(H_TOT, 16), blk, 0, stream>>>(
        Q2, K2, Vt, sink, v_nulls, ctxb);

    // output projection: plain bf16, split-K=6, partials in K2 region
    convt_kernel<<<dim3(24, 288), blk, 0, stream>>>(WO_w, wot, NQ, C_MODEL);
    gemm_bf16_kernel<<<dim3(6, 8, 6), blk, 0, stream>>>(
        ctxb, wot, outpart, T_SEQ, C_MODEL, NQ);
    reduce_kernel<<<dim3(768), blk, 0, stream>>>(
        outpart, out, mbias, 786432, C_MODEL, 6, 1.0f / 12.0f);
}